// Round 1
// baseline (199.159 us; speedup 1.0000x reference)
//
#include <hip/hip_runtime.h>

namespace {

constexpr int NROWS = 8192;  // N
constexpr int C = 1600;      // classes
constexpr int L = 4;         // hierarchy levels
constexpr int K = 256;       // labels per level

// Per-output-column provenance chain: v[0] = count (1..5), v[1..5] = source
// columns of the ORIGINAL input whose sum gives the final value. 16 B so the
// apply kernels fetch one chain with a single dwordx4 load.
struct alignas(16) Chain { short v[8]; };

// ---------------------------------------------------------------------------
// Build the per-column chains once per call (index data lives on device).
// cls : level i writes tgt_i[k] = old[src_i[k]] + orig[tgt_i[k]]
// box : level i writes src_i[k] = old[tgt_i[k]] + orig[src_i[k]]
// Backward walk from the highest level that wrote column x; each hop emits
// one original-column term. Max depth = L, plus the terminal read => <=5.
// ---------------------------------------------------------------------------
__global__ __launch_bounds__(256) void build_chains(
    const int* __restrict__ tgt, const int* __restrict__ src,
    Chain* __restrict__ ch_cls, Chain* __restrict__ ch_box) {
  __shared__ short tpos[L][C];  // tpos[i][c] = k if tgt[i][k]==c else -1
  __shared__ short spos[L][C];
  __shared__ short tg[L][K];
  __shared__ short sr[L][K];
  const int tid = threadIdx.x, nt = blockDim.x;

  for (int i = tid; i < L * C; i += nt) {
    (&tpos[0][0])[i] = -1;
    (&spos[0][0])[i] = -1;
  }
  __syncthreads();
  for (int i = tid; i < L * K; i += nt) {
    const int lvl = i / K, k = i % K;
    const int t = tgt[i], s = src[i];
    (&tg[0][0])[i] = (short)t;
    (&sr[0][0])[i] = (short)s;
    tpos[lvl][t] = (short)k;  // unique within a level (permutation slice)
    spos[lvl][s] = (short)k;
  }
  __syncthreads();

  for (int j = tid; j < C; j += nt) {
    // ---- cls chain ----
    {
      Chain c;
      int cnt = 0, x = j, lvl = L - 1;
      for (;;) {
        c.v[1 + cnt] = (short)x;
        ++cnt;
        int fi = -1, fk = -1;
        for (int i = lvl; i >= 0; --i) {
          const short p = tpos[i][x];
          if (p >= 0) { fi = i; fk = p; break; }
        }
        if (fi < 0) break;
        x = sr[fi][fk];
        lvl = fi - 1;
      }
      c.v[0] = (short)cnt;
      for (int t = cnt; t < 5; ++t) c.v[1 + t] = 0;
      c.v[6] = 0; c.v[7] = 0;
      ch_cls[j] = c;
    }
    // ---- box chain (src/tgt swapped) ----
    {
      Chain c;
      int cnt = 0, x = j, lvl = L - 1;
      for (;;) {
        c.v[1 + cnt] = (short)x;
        ++cnt;
        int fi = -1, fk = -1;
        for (int i = lvl; i >= 0; --i) {
          const short p = spos[i][x];
          if (p >= 0) { fi = i; fk = p; break; }
        }
        if (fi < 0) break;
        x = tg[fi][fk];
        lvl = fi - 1;
      }
      c.v[0] = (short)cnt;
      for (int t = cnt; t < 5; ++t) c.v[1 + t] = 0;
      c.v[6] = 0; c.v[7] = 0;
      ch_box[j] = c;
    }
  }
}

// ---------------------------------------------------------------------------
// cls: out[r][j] = sum_t logits[r][chain[j].v[1+t]]
// 4 rows per block: one chain fetch serves 4 rows; rows staged in LDS so
// every global element is read exactly once (coalesced) and gathers hit LDS.
// ---------------------------------------------------------------------------
constexpr int RPB = 4;  // 8192 % 4 == 0

__global__ __launch_bounds__(256) void cls_apply(
    const float* __restrict__ logits, const Chain* __restrict__ chain,
    float* __restrict__ out) {
  __shared__ float srow[RPB][C];  // 25.6 KB
  const int r0 = blockIdx.x * RPB;
  const int tid = threadIdx.x, nt = blockDim.x;

  for (int r = 0; r < RPB; ++r)
    for (int j = tid; j < C; j += nt)
      srow[r][j] = logits[(size_t)(r0 + r) * C + j];
  __syncthreads();

  for (int j = tid; j < C; j += nt) {
    const Chain c = chain[j];
    const int cnt = c.v[0];
    const int x0 = c.v[1];
    float s0 = srow[0][x0], s1 = srow[1][x0], s2 = srow[2][x0], s3 = srow[3][x0];
    for (int t = 1; t < cnt; ++t) {
      const int x = c.v[1 + t];
      s0 += srow[0][x]; s1 += srow[1][x]; s2 += srow[2][x]; s3 += srow[3][x];
    }
    out[(size_t)(r0 + 0) * C + j] = s0;
    out[(size_t)(r0 + 1) * C + j] = s1;
    out[(size_t)(r0 + 2) * C + j] = s2;
    out[(size_t)(r0 + 3) * C + j] = s3;
  }
}

// ---------------------------------------------------------------------------
// box: float4 per column; one row (25.6 KB) staged in LDS per block.
// ---------------------------------------------------------------------------
__global__ __launch_bounds__(256) void box_apply(
    const float4* __restrict__ box, const Chain* __restrict__ chain,
    float4* __restrict__ out) {
  __shared__ float4 srow[C];  // 25.6 KB
  const int row = blockIdx.x;
  const int tid = threadIdx.x, nt = blockDim.x;
  const float4* brow = box + (size_t)row * C;
  float4* orow = out + (size_t)row * C;

  for (int j = tid; j < C; j += nt) srow[j] = brow[j];
  __syncthreads();

  for (int j = tid; j < C; j += nt) {
    const Chain c = chain[j];
    const int cnt = c.v[0];
    float4 s = srow[c.v[1]];
    for (int t = 1; t < cnt; ++t) {
      const float4 a = srow[c.v[1 + t]];
      s.x += a.x; s.y += a.y; s.z += a.z; s.w += a.w;
    }
    orow[j] = s;
  }
}

}  // namespace

extern "C" void kernel_launch(void* const* d_in, const int* in_sizes, int n_in,
                              void* d_out, int out_size, void* d_ws, size_t ws_size,
                              hipStream_t stream) {
  const float* logits = (const float*)d_in[0];       // (N, C)
  const float* boxr   = (const float*)d_in[1];       // (N, 4C)
  const int*   tgt    = (const int*)d_in[2];         // (L, K)
  const int*   src    = (const int*)d_in[3];         // (L, K)

  float* out_cls = (float*)d_out;                    // (N, C)
  float* out_box = out_cls + (size_t)NROWS * C;      // (N, 4C)

  Chain* ch_cls = (Chain*)d_ws;                      // 25.6 KB
  Chain* ch_box = ch_cls + C;                        // 25.6 KB

  build_chains<<<1, 256, 0, stream>>>(tgt, src, ch_cls, ch_box);
  cls_apply<<<NROWS / RPB, 256, 0, stream>>>(logits, ch_cls, out_cls);
  box_apply<<<NROWS, 256, 0, stream>>>((const float4*)boxr, ch_box,
                                       (float4*)out_box);
}